// Round 12
// baseline (332.871 us; speedup 1.0000x reference)
//
#include <hip/hip_runtime.h>
#include <hip/hip_bf16.h>

#define N_NODES 50000
#define NE      800000
#define IN_DIM  256
#define H_DIM   128
#define NL      2
#define NR      8
#define RD_DIM  16
#define CONF_W  0.5f
#define LN_EPS  1e-5f

#define SCAN_CHUNK 1024
#define NB_SCAN    ((N_NODES + SCAN_CHUNK - 1) / SCAN_CHUNK)   // 49
#define DCAP       192   // per-wave LDS-cached edges (max deg ~45 for Poisson-16)

typedef __attribute__((ext_vector_type(8))) short bf16x8;
typedef __attribute__((ext_vector_type(4))) float f32x4;
typedef __attribute__((ext_vector_type(2))) float f32x2;

__device__ __forceinline__ unsigned short f2bf(float f) {
    unsigned u = __float_as_uint(f);
    u += 0x7fffu + ((u >> 16) & 1u);          // round-to-nearest-even
    return (unsigned short)(u >> 16);
}
__device__ __forceinline__ float bf_lo(unsigned v) {
    return __uint_as_float(v << 16);
}
__device__ __forceinline__ float bf_hi(unsigned v) {
    return __uint_as_float(v & 0xffff0000u);
}
__device__ __forceinline__ unsigned char f2fp8(float v) {   // OCP e4m3
    int pk = __builtin_amdgcn_cvt_pk_fp8_f32(v, v, 0, false);
    return (unsigned char)(pk & 0xff);
}

// ============ CSR build (dst is layer-invariant: build once per call) ============

__global__ void k_count(const int* __restrict__ dstv, int* __restrict__ counts,
                        int* __restrict__ rank) {
    int i = blockIdx.x * 256 + threadIdx.x;
    if (i >= NE) return;
    rank[i] = atomicAdd(counts + dstv[i], 1);
}

__global__ __launch_bounds__(256) void k_scan1(const int* __restrict__ counts,
                                               int* __restrict__ bsum) {
    __shared__ int lsum[256];
    const int t = threadIdx.x, b = blockIdx.x;
    const int base = b * SCAN_CHUNK + t * 4;
    int s = 0;
#pragma unroll
    for (int j = 0; j < 4; ++j) {
        int idx = base + j;
        if (idx < N_NODES) s += counts[idx];
    }
    lsum[t] = s;
    __syncthreads();
    for (int off = 128; off; off >>= 1) {
        if (t < off) lsum[t] += lsum[t + off];
        __syncthreads();
    }
    if (t == 0) bsum[b] = lsum[0];
}

__global__ void k_scan2(const int* __restrict__ bsum, int* __restrict__ bbase) {
    int lane = threadIdx.x & 63;
    int v = (lane < NB_SCAN) ? bsum[lane] : 0;
    int inc = v;
    for (int off = 1; off < 64; off <<= 1) {
        int tmp = __shfl_up(inc, off);
        if (lane >= off) inc += tmp;
    }
    if (lane < NB_SCAN) bbase[lane] = inc - v;   // exclusive
}

__global__ __launch_bounds__(256) void k_scan3(const int* __restrict__ counts,
                                               const int* __restrict__ bbase,
                                               int* __restrict__ offsets) {
    __shared__ int lsum[256];
    const int t = threadIdx.x, b = blockIdx.x;
    const int base = b * SCAN_CHUNK + t * 4;
    int c[4];
    int s = 0;
#pragma unroll
    for (int j = 0; j < 4; ++j) {
        int idx = base + j;
        c[j] = (idx < N_NODES) ? counts[idx] : 0;
        s += c[j];
    }
    lsum[t] = s;
    __syncthreads();
    for (int off = 1; off < 256; off <<= 1) {
        int v = (t >= off) ? lsum[t - off] : 0;
        __syncthreads();
        lsum[t] += v;
        __syncthreads();
    }
    int run = bbase[b] + lsum[t] - s;
#pragma unroll
    for (int j = 0; j < 4; ++j) {
        int idx = base + j;
        if (idx < N_NODES) { offsets[idx] = run; run += c[j]; }
    }
}

// scatter per-edge record {src|type<<16, bits(lc)} into dst-sorted order
__global__ void k_perm(const int* __restrict__ srcv, const int* __restrict__ dstv,
                       const int* __restrict__ et, const float* __restrict__ ea,
                       const int* __restrict__ offsets, const int* __restrict__ rank,
                       uint2* __restrict__ meta_sorted) {
    int i = blockIdx.x * 256 + threadIdx.x;
    if (i >= NE) return;
    int p = offsets[dstv[i]] + rank[i];
    int t = et[i]; t = t < 0 ? 0 : (t > NR - 1 ? NR - 1 : t);
    float lc = CONF_W * logf(fmaxf(ea[i], 1e-6f));
    meta_sorted[p] = make_uint2((unsigned)srcv[i] | ((unsigned)t << 16),
                                __float_as_uint(lc));
}

// ============ setup: weight cvt+transpose, zero counts/dsc/ssc, rel_score ============
__global__ void k_setup(const float* __restrict__ W_in,
                        const float* __restrict__ W_msg,
                        const float* __restrict__ rel_emb,
                        const float* __restrict__ W_rel,
                        const float* __restrict__ att_vec,
                        unsigned short* __restrict__ Wt_in,
                        unsigned short* __restrict__ Wt_msg,
                        float* __restrict__ dsc, float* __restrict__ ssc,
                        int* __restrict__ counts,
                        float* __restrict__ rel_score) {
    int i = blockIdx.x * 256 + threadIdx.x;
    if (i < H_DIM * IN_DIM) {                       // Wt_in[n*256+k] = W_in[k*128+n]
        int n = i >> 8, k = i & 255;
        Wt_in[i] = f2bf(W_in[(size_t)k * H_DIM + n]);
    } else if (i < H_DIM * IN_DIM + NL * H_DIM * H_DIM) {
        int r = i - H_DIM * IN_DIM;                 // Wt_msg[l][n*128+k] = W_msg[l][k*128+n]
        int l = r >> 14;
        int n = (r >> 7) & 127, k = r & 127;
        Wt_msg[r] = f2bf(W_msg[(size_t)l * H_DIM * H_DIM + (size_t)k * H_DIM + n]);
    }
    if (i < NL * N_NODES) { dsc[i] = 0.f; ssc[i] = 0.f; }
    if (i < N_NODES) counts[i] = 0;

    if (blockIdx.x == 0) {
        __shared__ float wvec[NL][RD_DIM];
        int t = threadIdx.x;
        if (t < NL * RD_DIM) {
            int l = t / RD_DIM, d = t % RD_DIM;
            const float* wr = W_rel + ((size_t)l * RD_DIM + d) * H_DIM;
            const float* ar = att_vec + (size_t)l * 3 * H_DIM + 2 * H_DIM;
            float s = 0.f;
            for (int k = 0; k < H_DIM; ++k) s += wr[k] * ar[k];
            wvec[l][d] = s;
        }
        __syncthreads();
        if (t < NL * NR) {
            int l = t / NR, r = t % NR;
            const float* re = rel_emb + ((size_t)l * NR + r) * RD_DIM;
            float s = 0.f;
            for (int d = 0; d < RD_DIM; ++d) s += re[d] * wvec[l][d];
            rel_score[t] = s;
        }
    }
}

// ============ bf16 MFMA GEMM: C[M x 128] = A[M x K] @ Wt^T ============
// BIASRELU: Cb16 = bf16(relu(C + bias))
// SCORES:   Cb8 = fp8_e4m3(C); dsc[m] += C_row.a_d, ssc[m] += C_row.a_s (fp32)
template <int K, bool ABF16, bool BIASRELU, bool SCORES>
__global__ __launch_bounds__(256) void k_gemm_mfma(
        const void* __restrict__ Av, const unsigned short* __restrict__ Bt,
        const float* __restrict__ bias,
        unsigned short* __restrict__ Cb16, unsigned char* __restrict__ Cb8, int M,
        const float* __restrict__ att_vec_l,
        float* __restrict__ dsc, float* __restrict__ ssc) {
    __shared__ unsigned short As[128 * 40];   // stride 40 bf16 = 80 B
    __shared__ unsigned short Bs[128 * 40];
    const int t = threadIdx.x;
    const int wid = t >> 6, lane = t & 63;
    const int wr = wid >> 1, wc = wid & 1;
    const int lm = lane & 15, lg = lane >> 4;
    const int m0 = blockIdx.x * 128;

    f32x4 acc[4][4] = {};

    for (int k0 = 0; k0 < K; k0 += 32) {
        if (ABF16) {
            const unsigned short* A = (const unsigned short*)Av;
#pragma unroll
            for (int i = 0; i < 2; ++i) {
                int flat = t + i * 256;
                int row = flat >> 2, ch = flat & 3;
                int rm = m0 + row; rm = rm < M ? rm : M - 1;
                uint4 v = *(const uint4*)(A + (size_t)rm * K + k0 + ch * 8);
                *(uint4*)(As + row * 40 + ch * 8) = v;
            }
        } else {
            const float* A = (const float*)Av;
#pragma unroll
            for (int i = 0; i < 4; ++i) {
                int flat = t + i * 256;
                int row = flat >> 3, c4 = flat & 7;
                int rm = m0 + row; rm = rm < M ? rm : M - 1;
                float4 fv = *(const float4*)(A + (size_t)rm * K + k0 + c4 * 4);
                uint2 pk;
                pk.x = (unsigned)f2bf(fv.x) | ((unsigned)f2bf(fv.y) << 16);
                pk.y = (unsigned)f2bf(fv.z) | ((unsigned)f2bf(fv.w) << 16);
                *(uint2*)(As + row * 40 + c4 * 4) = pk;
            }
        }
#pragma unroll
        for (int i = 0; i < 2; ++i) {
            int flat = t + i * 256;
            int row = flat >> 2, ch = flat & 3;
            uint4 v = *(const uint4*)(Bt + (size_t)row * K + k0 + ch * 8);
            *(uint4*)(Bs + row * 40 + ch * 8) = v;
        }
        __syncthreads();
        bf16x8 a[4], b[4];
#pragma unroll
        for (int f = 0; f < 4; ++f) {
            a[f] = *(const bf16x8*)(As + (wr * 64 + f * 16 + lm) * 40 + lg * 8);
            b[f] = *(const bf16x8*)(Bs + (wc * 64 + f * 16 + lm) * 40 + lg * 8);
        }
#pragma unroll
        for (int fm = 0; fm < 4; ++fm)
#pragma unroll
            for (int fn = 0; fn < 4; ++fn)
                acc[fm][fn] = __builtin_amdgcn_mfma_f32_16x16x32_bf16(
                    a[fm], b[fn], acc[fm][fn], 0, 0, 0);
        __syncthreads();
    }

    float av[4], asv[4];
    if (SCORES) {
#pragma unroll
        for (int fn = 0; fn < 4; ++fn) {
            int n = wc * 64 + fn * 16 + lm;
            av[fn]  = att_vec_l[n];
            asv[fn] = att_vec_l[H_DIM + n];
        }
    }

#pragma unroll
    for (int fm = 0; fm < 4; ++fm) {
#pragma unroll
        for (int j = 0; j < 4; ++j) {
            int m = m0 + wr * 64 + fm * 16 + lg * 4 + j;
            bool valid = m < M;
            if (BIASRELU) {
#pragma unroll
                for (int fn = 0; fn < 4; ++fn) {
                    int n = wc * 64 + fn * 16 + lm;
                    float v = fmaxf(acc[fm][fn][j] + bias[n], 0.f);
                    if (valid) Cb16[(size_t)m * H_DIM + n] = f2bf(v);
                }
            }
            if (SCORES) {
                float pd = 0.f, ps = 0.f;
#pragma unroll
                for (int fn = 0; fn < 4; ++fn) {
                    int n = wc * 64 + fn * 16 + lm;
                    float v = acc[fm][fn][j];
                    if (valid) Cb8[(size_t)m * H_DIM + n] = f2fp8(v);
                    pd += v * av[fn];
                    ps += v * asv[fn];
                }
#pragma unroll
                for (int off = 8; off; off >>= 1) {
                    pd += __shfl_xor(pd, off);
                    ps += __shfl_xor(ps, off);
                }
                if (lm == 0 && valid) {
                    atomicAdd(dsc + m, pd);
                    atomicAdd(ssc + m, ps);
                }
            }
        }
    }
}

// ============ fused per-node: softmax + branchless gather (fp8 hm) + LN ============
__global__ __launch_bounds__(256) void k_fused(
        const int* __restrict__ offsets, const int* __restrict__ counts,
        const uint2* __restrict__ meta,
        const float* __restrict__ dsc, const float* __restrict__ ssc,
        const float* __restrict__ rel_l,
        const unsigned char* __restrict__ hm,
        const unsigned short* __restrict__ h_in_bf,
        const float* __restrict__ bias_l, const float* __restrict__ g,
        const float* __restrict__ b,
        float* __restrict__ h_out_f32, unsigned short* __restrict__ h_out_bf) {
    __shared__ float rel_s[NR];
    __shared__ float es[4][DCAP];
    __shared__ unsigned srcoff[4][DCAP];
    if (threadIdx.x < NR) rel_s[threadIdx.x] = rel_l[threadIdx.x];
    __syncthreads();

    const int wave = threadIdx.x >> 6, lane = threadIdx.x & 63;
    const int sub = lane & 15, grp = lane >> 4;
    const int d = blockIdx.x * 4 + wave;   // grid exact: 12500*4 == 50000

    const int start = offsets[d];
    const int deg = counts[d];
    const float dsc_d = dsc[d];
    const int degc = deg < DCAP ? deg : DCAP;
    const int degp = (degc + 7) & ~7;

    // pass 1: logits once per edge -> LDS; wave max
    float m_l = -1e30f;
    for (int j = lane; j < deg; j += 64) {
        uint2 mv = meta[start + j];
        unsigned s = mv.x & 0xffff;
        float e = dsc_d + ssc[s] + rel_s[(mv.x >> 16) & 7];
        e = (e > 0.f ? e : 0.2f * e) + __uint_as_float(mv.y);
        if (j < DCAP) { es[wave][j] = e; srcoff[wave][j] = s * H_DIM; }  // fp8: 128 B rows
        m_l = fmaxf(m_l, e);
    }
    float m = m_l;
    for (int off = 32; off; off >>= 1) m = fmaxf(m, __shfl_xor(m, off));

    // pass 1.5: es -> w in place; pad to x8; ssum
    float s_l = 0.f;
    for (int j = lane; j < degp; j += 64) {
        float w = 0.f;
        if (j < degc) w = __expf(es[wave][j] - m);
        else srcoff[wave][j] = 0;
        es[wave][j] = w;
        s_l += w;
    }
    if (deg > DCAP) {      // never in practice (max deg ~45); uniform branch
        for (int j = DCAP + lane; j < deg; j += 64) {
            uint2 mv = meta[start + j];
            float e = dsc_d + ssc[mv.x & 0xffff] + rel_s[(mv.x >> 16) & 7];
            e = (e > 0.f ? e : 0.2f * e) + __uint_as_float(mv.y);
            s_l += __expf(e - m);
        }
    }
    float ssum = s_l;
    for (int off = 32; off; off >>= 1) ssum += __shfl_xor(ssum, off);

    __syncthreads();   // es/srcoff cross-lane visibility

    // pass 2: branchless 8-edges-per-iter gather (fp8 rows, 8 B/lane)
    float a0 = 0.f, a1 = 0.f, a2 = 0.f, a3 = 0.f,
          a4 = 0.f, a5 = 0.f, a6 = 0.f, a7 = 0.f;
    const char* hmp = (const char*)hm;
    for (int k0 = 0; k0 < degp; k0 += 8) {
        int ka = k0 + grp, kb = ka + 4;
        float wa = es[wave][ka];  unsigned oa = srcoff[wave][ka];
        float wb = es[wave][kb];  unsigned ob = srcoff[wave][kb];
        uint2 ra = *(const uint2*)(hmp + oa + sub * 8);
        uint2 rb = *(const uint2*)(hmp + ob + sub * 8);
        f32x2 pa0 = __builtin_amdgcn_cvt_pk_f32_fp8(ra.x, false);
        f32x2 pa1 = __builtin_amdgcn_cvt_pk_f32_fp8(ra.x, true);
        f32x2 pa2 = __builtin_amdgcn_cvt_pk_f32_fp8(ra.y, false);
        f32x2 pa3 = __builtin_amdgcn_cvt_pk_f32_fp8(ra.y, true);
        f32x2 pb0 = __builtin_amdgcn_cvt_pk_f32_fp8(rb.x, false);
        f32x2 pb1 = __builtin_amdgcn_cvt_pk_f32_fp8(rb.x, true);
        f32x2 pb2 = __builtin_amdgcn_cvt_pk_f32_fp8(rb.y, false);
        f32x2 pb3 = __builtin_amdgcn_cvt_pk_f32_fp8(rb.y, true);
        a0 += wa * pa0.x + wb * pb0.x;
        a1 += wa * pa0.y + wb * pb0.y;
        a2 += wa * pa1.x + wb * pb1.x;
        a3 += wa * pa1.y + wb * pb1.y;
        a4 += wa * pa2.x + wb * pb2.x;
        a5 += wa * pa2.y + wb * pb2.y;
        a6 += wa * pa3.x + wb * pb3.x;
        a7 += wa * pa3.y + wb * pb3.y;
    }
    if (deg > DCAP) {      // never in practice
        for (int k = DCAP + grp; k < deg; k += 4) {
            uint2 mv = meta[start + k];
            unsigned s = mv.x & 0xffff;
            float e = dsc_d + ssc[s] + rel_s[(mv.x >> 16) & 7];
            e = (e > 0.f ? e : 0.2f * e) + __uint_as_float(mv.y);
            float w = __expf(e - m);
            uint2 rv = *(const uint2*)(hmp + s * H_DIM + sub * 8);
            f32x2 p0 = __builtin_amdgcn_cvt_pk_f32_fp8(rv.x, false);
            f32x2 p1 = __builtin_amdgcn_cvt_pk_f32_fp8(rv.x, true);
            f32x2 p2 = __builtin_amdgcn_cvt_pk_f32_fp8(rv.y, false);
            f32x2 p3 = __builtin_amdgcn_cvt_pk_f32_fp8(rv.y, true);
            a0 += w * p0.x; a1 += w * p0.y;
            a2 += w * p1.x; a3 += w * p1.y;
            a4 += w * p2.x; a5 += w * p2.y;
            a6 += w * p3.x; a7 += w * p3.y;
        }
    }
    // merge the 4 edge-groups
    a0 += __shfl_xor(a0, 16); a1 += __shfl_xor(a1, 16);
    a2 += __shfl_xor(a2, 16); a3 += __shfl_xor(a3, 16);
    a4 += __shfl_xor(a4, 16); a5 += __shfl_xor(a5, 16);
    a6 += __shfl_xor(a6, 16); a7 += __shfl_xor(a7, 16);
    a0 += __shfl_xor(a0, 32); a1 += __shfl_xor(a1, 32);
    a2 += __shfl_xor(a2, 32); a3 += __shfl_xor(a3, 32);
    a4 += __shfl_xor(a4, 32); a5 += __shfl_xor(a5, 32);
    a6 += __shfl_xor(a6, 32); a7 += __shfl_xor(a7, 32);

    const float inv = (deg > 0) ? 1.f / ssum : 0.f;

    // residual (bf16) + bias + relu on channels sub*8 .. sub*8+7
    uint4 hv = *(const uint4*)(h_in_bf + (size_t)d * H_DIM + sub * 8);
    float4 b0 = *(const float4*)(bias_l + sub * 8);
    float4 b1 = *(const float4*)(bias_l + sub * 8 + 4);
    float v0 = bf_lo(hv.x) + fmaxf(a0 * inv + b0.x, 0.f);
    float v1 = bf_hi(hv.x) + fmaxf(a1 * inv + b0.y, 0.f);
    float v2 = bf_lo(hv.y) + fmaxf(a2 * inv + b0.z, 0.f);
    float v3 = bf_hi(hv.y) + fmaxf(a3 * inv + b0.w, 0.f);
    float v4 = bf_lo(hv.z) + fmaxf(a4 * inv + b1.x, 0.f);
    float v5 = bf_hi(hv.z) + fmaxf(a5 * inv + b1.y, 0.f);
    float v6 = bf_lo(hv.w) + fmaxf(a6 * inv + b1.z, 0.f);
    float v7 = bf_hi(hv.w) + fmaxf(a7 * inv + b1.w, 0.f);

    // layernorm: lanes hold 8 channels; 4 groups are duplicates -> divide by 512
    float sum = v0 + v1 + v2 + v3 + v4 + v5 + v6 + v7;
    for (int off = 32; off; off >>= 1) sum += __shfl_xor(sum, off);
    float mu = sum * (1.f / (H_DIM * 4));
    float d0 = v0 - mu, d1 = v1 - mu, d2 = v2 - mu, d3 = v3 - mu;
    float d4 = v4 - mu, d5 = v5 - mu, d6 = v6 - mu, d7 = v7 - mu;
    float vs = d0 * d0 + d1 * d1 + d2 * d2 + d3 * d3 +
               d4 * d4 + d5 * d5 + d6 * d6 + d7 * d7;
    for (int off = 32; off; off >>= 1) vs += __shfl_xor(vs, off);
    float invstd = rsqrtf(vs * (1.f / (H_DIM * 4)) + LN_EPS);

    float4 g0 = *(const float4*)(g + sub * 8);
    float4 g1 = *(const float4*)(g + sub * 8 + 4);
    float4 bb0 = *(const float4*)(b + sub * 8);
    float4 bb1 = *(const float4*)(b + sub * 8 + 4);
    float o0 = d0 * invstd * g0.x + bb0.x;
    float o1 = d1 * invstd * g0.y + bb0.y;
    float o2 = d2 * invstd * g0.z + bb0.z;
    float o3 = d3 * invstd * g0.w + bb0.w;
    float o4 = d4 * invstd * g1.x + bb1.x;
    float o5 = d5 * invstd * g1.y + bb1.y;
    float o6 = d6 * invstd * g1.z + bb1.z;
    float o7 = d7 * invstd * g1.w + bb1.w;

    if (grp == 0) {   // groups hold identical results; one group stores the row
        if (h_out_f32) {
            float* p = h_out_f32 + (size_t)d * H_DIM + sub * 8;
            *(float4*)p = make_float4(o0, o1, o2, o3);
            *(float4*)(p + 4) = make_float4(o4, o5, o6, o7);
        }
        if (h_out_bf) {
            uint4 pk;
            pk.x = (unsigned)f2bf(o0) | ((unsigned)f2bf(o1) << 16);
            pk.y = (unsigned)f2bf(o2) | ((unsigned)f2bf(o3) << 16);
            pk.z = (unsigned)f2bf(o4) | ((unsigned)f2bf(o5) << 16);
            pk.w = (unsigned)f2bf(o6) | ((unsigned)f2bf(o7) << 16);
            *(uint4*)(h_out_bf + (size_t)d * H_DIM + sub * 8) = pk;
        }
    }
}

extern "C" void kernel_launch(void* const* d_in, const int* in_sizes, int n_in,
                              void* d_out, int out_size, void* d_ws, size_t ws_size,
                              hipStream_t stream) {
    const float* x         = (const float*)d_in[0];
    const int*   edge_index= (const int*)d_in[1];
    const int*   edge_type = (const int*)d_in[2];
    const float* edge_attr = (const float*)d_in[3];
    const float* W_in      = (const float*)d_in[4];
    const float* b_in      = (const float*)d_in[5];
    const float* W_msg     = (const float*)d_in[6];
    const float* rel_emb   = (const float*)d_in[7];
    const float* W_rel     = (const float*)d_in[8];
    const float* att_vec   = (const float*)d_in[9];
    const float* bias      = (const float*)d_in[10];
    const float* ln_g      = (const float*)d_in[11];
    const float* ln_b      = (const float*)d_in[12];
    float* out = (float*)d_out;

    // workspace layout (~31 MB)
    char* w = (char*)d_ws;
    unsigned short* h_bf = (unsigned short*)w; w += (size_t)N_NODES * H_DIM * 2; // 12.8
    unsigned char* hm_f8 = (unsigned char*)w;  w += (size_t)N_NODES * H_DIM;     //  6.4
    uint2* meta_sorted = (uint2*)w; w += (size_t)NE * 8;               //  6.4 MB
    int*   rank       = (int*)w;   w += (size_t)NE * 4;                //  3.2 MB
    int*   counts     = (int*)w;   w += (size_t)N_NODES * 4;
    int*   offsets    = (int*)w;   w += (size_t)N_NODES * 4;
    float* dsc        = (float*)w; w += (size_t)NL * N_NODES * 4;
    float* ssc        = (float*)w; w += (size_t)NL * N_NODES * 4;
    unsigned short* Wt_in  = (unsigned short*)w; w += (size_t)H_DIM * IN_DIM * 2;
    unsigned short* Wt_msg = (unsigned short*)w; w += (size_t)NL * H_DIM * H_DIM * 2;
    float* rel_score  = (float*)w; w += 64 * 4;
    int*   bsum       = (int*)w;   w += 64 * 4;
    int*   bbase      = (int*)w;   w += 64 * 4;

    const int* srcv = edge_index;
    const int* dstv = edge_index + NE;

    // ---- setup (zeros counts/dsc/ssc, cvt weights, rel_score) then CSR build
    k_setup<<<(NL * N_NODES + 255) / 256, 256, 0, stream>>>(
        W_in, W_msg, rel_emb, W_rel, att_vec, Wt_in, Wt_msg, dsc, ssc, counts,
        rel_score);
    k_count<<<(NE + 255) / 256, 256, 0, stream>>>(dstv, counts, rank);
    k_scan1<<<NB_SCAN, 256, 0, stream>>>(counts, bsum);
    k_scan2<<<1, 64, 0, stream>>>(bsum, bbase);
    k_scan3<<<NB_SCAN, 256, 0, stream>>>(counts, bbase, offsets);
    k_perm<<<(NE + 255) / 256, 256, 0, stream>>>(srcv, dstv, edge_type, edge_attr,
                                                 offsets, rank, meta_sorted);

    const int GB = (N_NODES + 127) / 128;   // 391
    k_gemm_mfma<IN_DIM, false, true, false><<<GB, 256, 0, stream>>>(
        x, Wt_in, b_in, h_bf, nullptr, N_NODES, nullptr, nullptr, nullptr);

    for (int l = 0; l < NL; ++l) {
        k_gemm_mfma<H_DIM, true, false, true><<<GB, 256, 0, stream>>>(
            h_bf, Wt_msg + (size_t)l * H_DIM * H_DIM, nullptr, nullptr, hm_f8, N_NODES,
            att_vec + (size_t)l * 3 * H_DIM, dsc + (size_t)l * N_NODES,
            ssc + (size_t)l * N_NODES);
        k_fused<<<N_NODES / 4, 256, 0, stream>>>(
            offsets, counts, meta_sorted,
            dsc + (size_t)l * N_NODES, ssc + (size_t)l * N_NODES,
            rel_score + l * NR, hm_f8, h_bf,
            bias + (size_t)l * H_DIM, ln_g + (size_t)l * H_DIM,
            ln_b + (size_t)l * H_DIM,
            (l == NL - 1) ? out : nullptr,
            (l == NL - 1) ? nullptr : h_bf);
    }
}